// Round 1
// baseline (604.117 us; speedup 1.0000x reference)
//
#include <hip/hip_runtime.h>
#include <stdint.h>

typedef __bf16 bf16;
typedef bf16 bf16x8 __attribute__((ext_vector_type(8)));
typedef float f32x4 __attribute__((ext_vector_type(4)));

#define LOG2E 1.4426950408889634f
#define SQRT_E 27.712812921102035f

constexpr int BM = 128, BN = 128, BK = 32;
enum { EPI_F32 = 0, EPI_HILO = 1, EPI_VT = 2 };

__device__ __forceinline__ void async16(const void* g, void* l) {
  __builtin_amdgcn_global_load_lds(
      (__attribute__((address_space(1))) void*)(uintptr_t)g,
      (__attribute__((address_space(3))) void*)l, 16, 0, 0);
}

// C[M,N] = A[M,K] * B[N,K]^T  (NT layout, K contiguous in both operands).
// TERMS==3: A,B each given as hi/lo bf16 split; accumulate hi*hi + hi*lo + lo*hi.
template <int TERMS, int EPI>
__global__ __launch_bounds__(256)
void gemm_kernel(const bf16* __restrict__ Ah, const bf16* __restrict__ Al,
                 const bf16* __restrict__ Bh, const bf16* __restrict__ Bl,
                 void* __restrict__ C0, void* __restrict__ C1,
                 int K, long lda, long ldb, long ldc,
                 long sA, long sB, long sC) {
  __shared__ __align__(16) bf16 sAh[BM * BK];
  __shared__ __align__(16) bf16 sBh[BN * BK];
  __shared__ __align__(16) bf16 sAl[TERMS == 3 ? BM * BK : 8];
  __shared__ __align__(16) bf16 sBl[TERMS == 3 ? BN * BK : 8];

  const int z = blockIdx.z;
  const bf16* pAh = Ah + (long)z * sA;
  const bf16* pBh = Bh + (long)z * sB;
  const bf16* pAl = (TERMS == 3) ? (Al + (long)z * sA) : nullptr;
  const bf16* pBl = (TERMS == 3) ? (Bl + (long)z * sB) : nullptr;

  const int bm = blockIdx.y * BM;
  const int bn = blockIdx.x * BN;
  const int tid = threadIdx.x;
  const int wave = tid >> 6;
  const int lane = tid & 63;
  const int wm = (wave & 1) * 64;
  const int wn = (wave >> 1) * 64;
  const int quad = lane >> 4;
  const int l16 = lane & 15;

  f32x4 acc[4][4] = {};

  // staging: 512 chunks of 16B per 128x32 tile; thread handles chunk tid and tid+256
  const int r0 = tid >> 2;          // row 0..63
  const int p0 = (tid & 3) * 8;     // k-offset in elements

  for (int kt = 0; kt < K; kt += BK) {
    __syncthreads();
    {
      const long ka = kt + p0;
      async16(pAh + (long)(bm + r0) * lda + ka,      &sAh[tid * 8]);
      async16(pAh + (long)(bm + 64 + r0) * lda + ka, &sAh[(tid + 256) * 8]);
      async16(pBh + (long)(bn + r0) * ldb + ka,      &sBh[tid * 8]);
      async16(pBh + (long)(bn + 64 + r0) * ldb + ka, &sBh[(tid + 256) * 8]);
      if constexpr (TERMS == 3) {
        async16(pAl + (long)(bm + r0) * lda + ka,      &sAl[tid * 8]);
        async16(pAl + (long)(bm + 64 + r0) * lda + ka, &sAl[(tid + 256) * 8]);
        async16(pBl + (long)(bn + r0) * ldb + ka,      &sBl[tid * 8]);
        async16(pBl + (long)(bn + 64 + r0) * ldb + ka, &sBl[(tid + 256) * 8]);
      }
    }
    __syncthreads();

    bf16x8 ah[4], al[4];
#pragma unroll
    for (int i = 0; i < 4; ++i) {
      ah[i] = *(const bf16x8*)&sAh[(wm + i * 16 + l16) * BK + quad * 8];
      if constexpr (TERMS == 3)
        al[i] = *(const bf16x8*)&sAl[(wm + i * 16 + l16) * BK + quad * 8];
    }
#pragma unroll
    for (int j = 0; j < 4; ++j) {
      const bf16x8 bh = *(const bf16x8*)&sBh[(wn + j * 16 + l16) * BK + quad * 8];
      if constexpr (TERMS == 3) {
        const bf16x8 bl = *(const bf16x8*)&sBl[(wn + j * 16 + l16) * BK + quad * 8];
#pragma unroll
        for (int i = 0; i < 4; ++i) {
          acc[i][j] = __builtin_amdgcn_mfma_f32_16x16x32_bf16(ah[i], bh, acc[i][j], 0, 0, 0);
          acc[i][j] = __builtin_amdgcn_mfma_f32_16x16x32_bf16(ah[i], bl, acc[i][j], 0, 0, 0);
          acc[i][j] = __builtin_amdgcn_mfma_f32_16x16x32_bf16(al[i], bh, acc[i][j], 0, 0, 0);
        }
      } else {
#pragma unroll
        for (int i = 0; i < 4; ++i)
          acc[i][j] = __builtin_amdgcn_mfma_f32_16x16x32_bf16(ah[i], bh, acc[i][j], 0, 0, 0);
      }
    }
  }

  // C/D frag mapping (m89/m91 verified): col = lane&15, row = quad*4 + reg
  if constexpr (EPI == EPI_F32) {
    float* C = (float*)C0 + (long)z * sC;
#pragma unroll
    for (int i = 0; i < 4; ++i) {
      const int mb = bm + wm + i * 16 + quad * 4;
#pragma unroll
      for (int j = 0; j < 4; ++j) {
        const int n = bn + wn + j * 16 + l16;
#pragma unroll
        for (int r = 0; r < 4; ++r)
          C[(long)(mb + r) * ldc + n] = acc[i][j][r];
      }
    }
  } else if constexpr (EPI == EPI_HILO) {
    bf16* Ch = (bf16*)C0;
    bf16* Cl = (bf16*)C1;
#pragma unroll
    for (int i = 0; i < 4; ++i) {
      const int mb = bm + wm + i * 16 + quad * 4;
#pragma unroll
      for (int j = 0; j < 4; ++j) {
        const int n = bn + wn + j * 16 + l16;
#pragma unroll
        for (int r = 0; r < 4; ++r) {
          const float f = acc[i][j][r];
          const bf16 h = (bf16)f;
          const long idx = (long)(mb + r) * ldc + n;
          Ch[idx] = h;
          Cl[idx] = (bf16)(f - (float)h);
        }
      }
    }
  } else {  // EPI_VT: C0 = vT [8][768][2048] bf16, global row m -> (batch m>>11, m&2047)
    bf16* vT = (bf16*)C0;
#pragma unroll
    for (int i = 0; i < 4; ++i) {
      const int mb = bm + wm + i * 16 + quad * 4;
      const long bb = mb >> 11;
      const long ml = mb & 2047;
#pragma unroll
      for (int j = 0; j < 4; ++j) {
        const int e = bn + wn + j * 16 + l16;
        union { bf16 b[4]; uint2 u; } P;
#pragma unroll
        for (int r = 0; r < 4; ++r) P.b[r] = (bf16)acc[i][j][r];
        *(uint2*)&vT[(bb * 768 + e) * 2048 + ml] = P.u;
      }
    }
  }
}

// One block per score row (2048 fp32). Writes normalized p * (1/sqrt(768)) as
// bf16 IN-PLACE into the first half of the row's fp32 storage (all reads
// complete before the reduction barriers; all writes after).
__global__ __launch_bounds__(256)
void softmax_kernel(float* __restrict__ sc) {
  __shared__ float red[4];
  float* srow = sc + (long)blockIdx.x * 2048;
  const int tid = threadIdx.x;
  const int wave = tid >> 6;
  const int lane = tid & 63;
  const float4 v0 = *(const float4*)(srow + tid * 4);
  const float4 v1 = *(const float4*)(srow + 1024 + tid * 4);
  float mx = fmaxf(fmaxf(fmaxf(v0.x, v0.y), fmaxf(v0.z, v0.w)),
                   fmaxf(fmaxf(v1.x, v1.y), fmaxf(v1.z, v1.w)));
#pragma unroll
  for (int o = 32; o >= 1; o >>= 1) mx = fmaxf(mx, __shfl_xor(mx, o));
  if (lane == 0) red[wave] = mx;
  __syncthreads();
  mx = fmaxf(fmaxf(red[0], red[1]), fmaxf(red[2], red[3]));
  const float e0 = exp2f((v0.x - mx) * LOG2E);
  const float e1 = exp2f((v0.y - mx) * LOG2E);
  const float e2 = exp2f((v0.z - mx) * LOG2E);
  const float e3 = exp2f((v0.w - mx) * LOG2E);
  const float e4 = exp2f((v1.x - mx) * LOG2E);
  const float e5 = exp2f((v1.y - mx) * LOG2E);
  const float e6 = exp2f((v1.z - mx) * LOG2E);
  const float e7 = exp2f((v1.w - mx) * LOG2E);
  float s = ((e0 + e1) + (e2 + e3)) + ((e4 + e5) + (e6 + e7));
#pragma unroll
  for (int o = 32; o >= 1; o >>= 1) s += __shfl_xor(s, o);
  __syncthreads();  // everyone done reading red[] for max
  if (lane == 0) red[wave] = s;
  __syncthreads();
  s = red[0] + red[1] + red[2] + red[3];
  const float inv = 1.0f / (s * SQRT_E);
  bf16* prow = (bf16*)srow;
  union { bf16 b[4]; uint2 u; } P;
  P.b[0] = (bf16)(e0 * inv); P.b[1] = (bf16)(e1 * inv);
  P.b[2] = (bf16)(e2 * inv); P.b[3] = (bf16)(e3 * inv);
  *(uint2*)(prow + tid * 4) = P.u;
  P.b[0] = (bf16)(e4 * inv); P.b[1] = (bf16)(e5 * inv);
  P.b[2] = (bf16)(e6 * inv); P.b[3] = (bf16)(e7 * inv);
  *(uint2*)(prow + 1024 + tid * 4) = P.u;
}

// fp32 -> bf16 hi (+ optional lo residual), 4 elements/thread
__global__ __launch_bounds__(256)
void split_kernel(const float* __restrict__ src, bf16* __restrict__ hi,
                  bf16* __restrict__ lo, int n4) {
  const int i = blockIdx.x * 256 + threadIdx.x;
  if (i >= n4) return;
  const float4 v = ((const float4*)src)[i];
  const bf16 h0 = (bf16)v.x, h1 = (bf16)v.y, h2 = (bf16)v.z, h3 = (bf16)v.w;
  union { bf16 b[4]; uint2 u; } P;
  P.b[0] = h0; P.b[1] = h1; P.b[2] = h2; P.b[3] = h3;
  ((uint2*)hi)[i] = P.u;
  if (lo != nullptr) {
    P.b[0] = (bf16)(v.x - (float)h0);
    P.b[1] = (bf16)(v.y - (float)h1);
    P.b[2] = (bf16)(v.z - (float)h2);
    P.b[3] = (bf16)(v.w - (float)h3);
    ((uint2*)lo)[i] = P.u;
  }
}

extern "C" void kernel_launch(void* const* d_in, const int* in_sizes, int n_in,
                              void* d_out, int out_size, void* d_ws, size_t ws_size,
                              hipStream_t stream) {
  const float* x  = (const float*)d_in[0];
  const float* Wq = (const float*)d_in[1];
  const float* Wk = (const float*)d_in[2];
  const float* Wv = (const float*)d_in[3];
  float* out = (float*)d_out;
  char* ws = (char*)d_ws;

  // ---- workspace layout ----
  const size_t SZQ = 25165824;   // 16384*768 bf16
  bf16* qh = (bf16*)(ws + 0 * SZQ);
  bf16* ql = (bf16*)(ws + 1 * SZQ);
  bf16* kh = (bf16*)(ws + 2 * SZQ);
  bf16* kl = (bf16*)(ws + 3 * SZQ);
  bf16* vT = (bf16*)(ws + 4 * SZQ);
  const size_t PERS = 5 * SZQ;   // 125829120 bytes persistent
  // phase-1 temps (dead once GEMM1 finishes); scores region overlays them
  bf16* xh = (bf16*)(ws + PERS);
  bf16* xl = (bf16*)(ws + PERS + SZQ);
  const size_t WSZ = 1179648;    // 768*768 bf16
  char* wbase = ws + PERS + 2 * SZQ;
  bf16* wqh = (bf16*)(wbase + 0 * WSZ);
  bf16* wql = (bf16*)(wbase + 1 * WSZ);
  bf16* wkh = (bf16*)(wbase + 2 * WSZ);
  bf16* wkl = (bf16*)(wbase + 3 * WSZ);
  bf16* wvh = (bf16*)(wbase + 4 * WSZ);
  float* scores = (float*)(ws + PERS);

  long avail = (long)ws_size - (long)PERS;
  int nb = (int)(avail / 16777216);  // batches of fp32 [2048,2048] scores that fit
  if (nb < 1) nb = 1;
  if (nb > 8) nb = 8;

  // ---- phase 1: convert + QKV projections ----
  split_kernel<<<12288, 256, 0, stream>>>(x, xh, xl, 3145728);
  split_kernel<<<576, 256, 0, stream>>>(Wq, wqh, wql, 147456);
  split_kernel<<<576, 256, 0, stream>>>(Wk, wkh, wkl, 147456);
  split_kernel<<<576, 256, 0, stream>>>(Wv, wvh, nullptr, 147456);

  dim3 g1(6, 128, 1);
  gemm_kernel<3, EPI_HILO><<<g1, 256, 0, stream>>>(xh, xl, wqh, wql,
      (void*)qh, (void*)ql, 768, 768, 768, 768, 0, 0, 0);
  gemm_kernel<3, EPI_HILO><<<g1, 256, 0, stream>>>(xh, xl, wkh, wkl,
      (void*)kh, (void*)kl, 768, 768, 768, 768, 0, 0, 0);
  gemm_kernel<1, EPI_VT><<<g1, 256, 0, stream>>>(xh, nullptr, wvh, nullptr,
      (void*)vT, nullptr, 768, 768, 768, 0, 0, 0, 0);

  // ---- phase 2: scores -> softmax -> PV, in batch groups ----
  const long QS = 1572864;  // 2048*768
  for (int b0 = 0; b0 < 8; b0 += nb) {
    const int nbg = (8 - b0 < nb) ? (8 - b0) : nb;
    dim3 g2(16, 16, nbg);
    gemm_kernel<3, EPI_F32><<<g2, 256, 0, stream>>>(
        qh + (long)b0 * QS, ql + (long)b0 * QS,
        kh + (long)b0 * QS, kl + (long)b0 * QS,
        (void*)scores, nullptr, 768, 768, 768, 2048, QS, QS, 4194304L);
    softmax_kernel<<<nbg * 2048, 256, 0, stream>>>(scores);
    dim3 g3(6, 16, nbg);
    // A = p (bf16 rows embedded in fp32 score rows, element pitch 4096)
    gemm_kernel<1, EPI_F32><<<g3, 256, 0, stream>>>(
        (const bf16*)scores, nullptr, vT + (long)b0 * QS, nullptr,
        (void*)(out + (long)b0 * QS), nullptr,
        2048, 4096, 2048, 768, 8388608L, QS, QS);
  }
}

// Round 2
// 528.661 us; speedup vs baseline: 1.1427x; 1.1427x over previous
//
#include <hip/hip_runtime.h>
#include <stdint.h>
#include <type_traits>

typedef __bf16 bf16;
typedef _Float16 f16;
typedef bf16 bf16x8 __attribute__((ext_vector_type(8)));
typedef f16 f16x8 __attribute__((ext_vector_type(8)));
typedef float f32x4 __attribute__((ext_vector_type(4)));

#define LOG2E 1.4426950408889634f
#define SQRT_E 27.712812921102035f

constexpr int BM = 128, BN = 128, BK = 32;
enum { EPI_F32 = 0, EPI_PAIR = 1, EPI_VT = 2 };

__device__ __forceinline__ void async16(const void* g, void* l) {
  __builtin_amdgcn_global_load_lds(
      (__attribute__((address_space(1))) void*)(uintptr_t)g,
      (__attribute__((address_space(3))) void*)l, 16, 0, 0);
}

__device__ __forceinline__ f32x4 mfma8(bf16x8 a, bf16x8 b, f32x4 c) {
  return __builtin_amdgcn_mfma_f32_16x16x32_bf16(a, b, c, 0, 0, 0);
}
__device__ __forceinline__ f32x4 mfma8(f16x8 a, f16x8 b, f32x4 c) {
  return __builtin_amdgcn_mfma_f32_16x16x32_f16(a, b, c, 0, 0, 0);
}

// C[M,N] = A[M,K] * B[N,K]^T (NT layout, K contiguous in both operands).
// AT/BT = digit tensors staged per operand. Terms computed: all (ai,bi) with
// ai+bi < 2  ->  (2,2): hh+hl+lh  (1,2): hh+hl  (1,1): hh.
template <typename T, typename TO, int AT, int BT, int EPI>
__global__ __launch_bounds__(256)
void gemm_kernel(const T* __restrict__ Ah, const T* __restrict__ Al,
                 const T* __restrict__ Bh, const T* __restrict__ Bl,
                 void* __restrict__ C0, void* __restrict__ C1,
                 int K, long lda, long ldb, long ldc,
                 long sA, long sB, long sC) {
  using vec8 = typename std::conditional<std::is_same<T, bf16>::value,
                                         bf16x8, f16x8>::type;
  __shared__ __align__(16) T sAh[BM * BK];
  __shared__ __align__(16) T sBh[BN * BK];
  __shared__ __align__(16) T sAl[AT == 2 ? BM * BK : 8];
  __shared__ __align__(16) T sBl[BT == 2 ? BN * BK : 8];

  const int z = blockIdx.z;
  const T* pAh = Ah + (long)z * sA;
  const T* pBh = Bh + (long)z * sB;
  const T* pAl = (AT == 2) ? (Al + (long)z * sA) : nullptr;
  const T* pBl = (BT == 2) ? (Bl + (long)z * sB) : nullptr;

  const int bm = blockIdx.y * BM;
  const int bn = blockIdx.x * BN;
  const int tid = threadIdx.x;
  const int wave = tid >> 6;
  const int lane = tid & 63;
  const int wm = (wave & 1) * 64;
  const int wn = (wave >> 1) * 64;
  const int quad = lane >> 4;
  const int l16 = lane & 15;

  f32x4 acc[4][4] = {};

  const int r0 = tid >> 2;        // staging row 0..63
  const int p0 = (tid & 3) * 8;   // staging k-offset (elements)

  for (int kt = 0; kt < K; kt += BK) {
    __syncthreads();
    {
      const long ka = kt + p0;
      async16(pAh + (long)(bm + r0) * lda + ka,      &sAh[tid * 8]);
      async16(pAh + (long)(bm + 64 + r0) * lda + ka, &sAh[(tid + 256) * 8]);
      async16(pBh + (long)(bn + r0) * ldb + ka,      &sBh[tid * 8]);
      async16(pBh + (long)(bn + 64 + r0) * ldb + ka, &sBh[(tid + 256) * 8]);
      if constexpr (AT == 2) {
        async16(pAl + (long)(bm + r0) * lda + ka,      &sAl[tid * 8]);
        async16(pAl + (long)(bm + 64 + r0) * lda + ka, &sAl[(tid + 256) * 8]);
      }
      if constexpr (BT == 2) {
        async16(pBl + (long)(bn + r0) * ldb + ka,      &sBl[tid * 8]);
        async16(pBl + (long)(bn + 64 + r0) * ldb + ka, &sBl[(tid + 256) * 8]);
      }
    }
    __syncthreads();

    vec8 ah[4], al[4];
#pragma unroll
    for (int i = 0; i < 4; ++i) {
      ah[i] = *(const vec8*)&sAh[(wm + i * 16 + l16) * BK + quad * 8];
      if constexpr (AT == 2)
        al[i] = *(const vec8*)&sAl[(wm + i * 16 + l16) * BK + quad * 8];
    }
#pragma unroll
    for (int j = 0; j < 4; ++j) {
      const vec8 bh = *(const vec8*)&sBh[(wn + j * 16 + l16) * BK + quad * 8];
      vec8 bl;
      if constexpr (BT == 2)
        bl = *(const vec8*)&sBl[(wn + j * 16 + l16) * BK + quad * 8];
#pragma unroll
      for (int i = 0; i < 4; ++i) {
        acc[i][j] = mfma8(ah[i], bh, acc[i][j]);
        if constexpr (BT == 2) acc[i][j] = mfma8(ah[i], bl, acc[i][j]);
        if constexpr (AT == 2) acc[i][j] = mfma8(al[i], bh, acc[i][j]);
      }
    }
  }

  // C/D frag mapping (m89/m91 verified): col = lane&15, row = quad*4 + reg
  if constexpr (EPI == EPI_F32) {
    float* C = (float*)C0 + (long)z * sC;
#pragma unroll
    for (int i = 0; i < 4; ++i) {
      const int mb = bm + wm + i * 16 + quad * 4;
#pragma unroll
      for (int j = 0; j < 4; ++j) {
        const int n = bn + wn + j * 16 + l16;
#pragma unroll
        for (int r = 0; r < 4; ++r)
          C[(long)(mb + r) * ldc + n] = acc[i][j][r];
      }
    }
  } else if constexpr (EPI == EPI_PAIR) {
    TO* Ch = (TO*)C0;
    TO* Cl = (TO*)C1;
#pragma unroll
    for (int i = 0; i < 4; ++i) {
      const int mb = bm + wm + i * 16 + quad * 4;
#pragma unroll
      for (int j = 0; j < 4; ++j) {
        const int n = bn + wn + j * 16 + l16;
#pragma unroll
        for (int r = 0; r < 4; ++r) {
          const float f = acc[i][j][r];
          const TO h = (TO)f;
          const long idx = (long)(mb + r) * ldc + n;
          Ch[idx] = h;
          Cl[idx] = (TO)(f - (float)h);
        }
      }
    }
  } else {  // EPI_VT: C0 = vT [8][768][2048], global row m -> (m>>11, m&2047)
    TO* vT = (TO*)C0;
#pragma unroll
    for (int i = 0; i < 4; ++i) {
      const int mb = bm + wm + i * 16 + quad * 4;
      const long bb = mb >> 11;
      const long ml = mb & 2047;
#pragma unroll
      for (int j = 0; j < 4; ++j) {
        const int e = bn + wn + j * 16 + l16;
        union { TO b[4]; uint2 u; } P;
#pragma unroll
        for (int r = 0; r < 4; ++r) P.b[r] = (TO)acc[i][j][r];
        *(uint2*)&vT[(bb * 768 + e) * 2048 + ml] = P.u;
      }
    }
  }
}

// One block per score row (2048 fp32). Writes normalized p * (1/sqrt(768)) as
// f16 IN-PLACE into the first quarter of the row's fp32 storage (all global
// reads are register-held before the final barriers; writes after).
__global__ __launch_bounds__(256)
void softmax_kernel(float* __restrict__ sc) {
  __shared__ float red[4];
  float* srow = sc + (long)blockIdx.x * 2048;
  const int tid = threadIdx.x;
  const int wave = tid >> 6;
  const int lane = tid & 63;
  const float4 v0 = *(const float4*)(srow + tid * 4);
  const float4 v1 = *(const float4*)(srow + 1024 + tid * 4);
  float mx = fmaxf(fmaxf(fmaxf(v0.x, v0.y), fmaxf(v0.z, v0.w)),
                   fmaxf(fmaxf(v1.x, v1.y), fmaxf(v1.z, v1.w)));
#pragma unroll
  for (int o = 32; o >= 1; o >>= 1) mx = fmaxf(mx, __shfl_xor(mx, o));
  if (lane == 0) red[wave] = mx;
  __syncthreads();
  mx = fmaxf(fmaxf(red[0], red[1]), fmaxf(red[2], red[3]));
  const float e0 = exp2f((v0.x - mx) * LOG2E);
  const float e1 = exp2f((v0.y - mx) * LOG2E);
  const float e2 = exp2f((v0.z - mx) * LOG2E);
  const float e3 = exp2f((v0.w - mx) * LOG2E);
  const float e4 = exp2f((v1.x - mx) * LOG2E);
  const float e5 = exp2f((v1.y - mx) * LOG2E);
  const float e6 = exp2f((v1.z - mx) * LOG2E);
  const float e7 = exp2f((v1.w - mx) * LOG2E);
  float s = ((e0 + e1) + (e2 + e3)) + ((e4 + e5) + (e6 + e7));
#pragma unroll
  for (int o = 32; o >= 1; o >>= 1) s += __shfl_xor(s, o);
  __syncthreads();  // everyone done reading red[] for max
  if (lane == 0) red[wave] = s;
  __syncthreads();
  s = red[0] + red[1] + red[2] + red[3];
  const float inv = 1.0f / (s * SQRT_E);
  f16* prow = (f16*)srow;
  union { f16 b[4]; uint2 u; } P;
  P.b[0] = (f16)(e0 * inv); P.b[1] = (f16)(e1 * inv);
  P.b[2] = (f16)(e2 * inv); P.b[3] = (f16)(e3 * inv);
  *(uint2*)(prow + tid * 4) = P.u;
  P.b[0] = (f16)(e4 * inv); P.b[1] = (f16)(e5 * inv);
  P.b[2] = (f16)(e6 * inv); P.b[3] = (f16)(e7 * inv);
  *(uint2*)(prow + 1024 + tid * 4) = P.u;
}

// Fused fp32 -> bf16 hi/lo split for x, Wq|Wk (concatenated dest), Wv (hi only).
__global__ __launch_bounds__(256)
void split_all(const float4* __restrict__ x, const float4* __restrict__ wq,
               const float4* __restrict__ wk, const float4* __restrict__ wv,
               uint2* __restrict__ xh, uint2* __restrict__ xl,
               uint2* __restrict__ wqkh, uint2* __restrict__ wqkl,
               uint2* __restrict__ wvh) {
  constexpr int NX = 3145728;   // x float4 count
  constexpr int NW = 147456;    // per-W float4 count
  const int i = blockIdx.x * 256 + threadIdx.x;
  float4 v;
  uint2 *dh, *dl;
  if (i < NX) {
    v = x[i]; dh = xh + i; dl = xl + i;
  } else {
    const int j = i - NX;
    if (j < 2 * NW) {
      v = (j < NW) ? wq[j] : wk[j - NW];
      dh = wqkh + j; dl = wqkl + j;
    } else {
      const int m = j - 2 * NW;
      v = wv[m]; dh = wvh + m; dl = nullptr;
    }
  }
  const bf16 h0 = (bf16)v.x, h1 = (bf16)v.y, h2 = (bf16)v.z, h3 = (bf16)v.w;
  union { bf16 b[4]; uint2 u; } P;
  P.b[0] = h0; P.b[1] = h1; P.b[2] = h2; P.b[3] = h3;
  *dh = P.u;
  if (dl != nullptr) {
    P.b[0] = (bf16)(v.x - (float)h0);
    P.b[1] = (bf16)(v.y - (float)h1);
    P.b[2] = (bf16)(v.z - (float)h2);
    P.b[3] = (bf16)(v.w - (float)h3);
    *dl = P.u;
  }
}

extern "C" void kernel_launch(void* const* d_in, const int* in_sizes, int n_in,
                              void* d_out, int out_size, void* d_ws, size_t ws_size,
                              hipStream_t stream) {
  const float* x  = (const float*)d_in[0];
  const float* Wq = (const float*)d_in[1];
  const float* Wk = (const float*)d_in[2];
  const float* Wv = (const float*)d_in[3];
  float* out = (float*)d_out;
  char* ws = (char*)d_ws;

  // ---- workspace layout (bytes) ----
  // persistent: qk fp16 pair [16384,1536] + vT f16 [8][768][2048]
  const size_t SZQK = 50331648;   // 16384*1536*2
  const size_t SZVT = 25165824;   // 16384*768*2
  f16* qkh = (f16*)(ws + 0);
  f16* qkl = (f16*)(ws + SZQK);
  f16* vT  = (f16*)(ws + 2 * SZQK);
  const size_t PERS = 2 * SZQK + SZVT;  // 125829120
  // phase-1 temps (dead after projections); scores overlays them
  const size_t SZX = 25165824;    // 16384*768 bf16
  bf16* xh = (bf16*)(ws + PERS);
  bf16* xl = (bf16*)(ws + PERS + SZX);
  const size_t SZWQK = 2359296;   // 1536*768 bf16
  bf16* wqkh = (bf16*)(ws + PERS + 2 * SZX);
  bf16* wqkl = (bf16*)(ws + PERS + 2 * SZX + SZWQK);
  bf16* wvh  = (bf16*)(ws + PERS + 2 * SZX + 2 * SZWQK);
  float* scores = (float*)(ws + PERS);

  long avail = (long)ws_size - (long)PERS;
  int nb = (int)(avail / 16777216);  // fp32 [2048,2048] score slabs that fit
  if (nb < 1) nb = 1;
  if (nb > 8) nb = 8;

  // ---- phase 1: fused split + projections ----
  split_all<<<14016, 256, 0, stream>>>(
      (const float4*)x, (const float4*)Wq, (const float4*)Wk, (const float4*)Wv,
      (uint2*)xh, (uint2*)xl, (uint2*)wqkh, (uint2*)wqkl, (uint2*)wvh);

  // q|k projection: [16384,768] x [1536,768]^T -> fp16 hi/lo pair, ldc=1536
  gemm_kernel<bf16, f16, 2, 2, EPI_PAIR><<<dim3(12, 128, 1), 256, 0, stream>>>(
      xh, xl, wqkh, wqkl, (void*)qkh, (void*)qkl, 768, 768, 768, 1536, 0, 0, 0);
  // v projection -> vT f16 transposed
  gemm_kernel<bf16, f16, 1, 1, EPI_VT><<<dim3(6, 128, 1), 256, 0, stream>>>(
      xh, nullptr, wvh, nullptr, (void*)vT, nullptr, 768, 768, 768, 0, 0, 0, 0);

  // ---- phase 2: scores -> softmax -> PV ----
  const long QKS = 3145728;  // 2048*1536 (qk batch stride, elements)
  const long VTS = 1572864;  // 768*2048
  for (int b0 = 0; b0 < 8; b0 += nb) {
    const int nbg = (8 - b0 < nb) ? (8 - b0) : nb;
    // S = qh * kh^T + qh * kl^T   (A = q single, B = k fp16 pair)
    gemm_kernel<f16, float, 1, 2, EPI_F32><<<dim3(16, 16, nbg), 256, 0, stream>>>(
        qkh + (long)b0 * QKS, nullptr,
        qkh + 768 + (long)b0 * QKS, qkl + 768 + (long)b0 * QKS,
        (void*)scores, nullptr, 768, 1536, 1536, 2048, QKS, QKS, 4194304L);
    softmax_kernel<<<nbg * 2048, 256, 0, stream>>>(scores);
    // O = P * vT^T  (P f16 rows embedded in fp32 score rows, pitch 4096 elems)
    gemm_kernel<f16, float, 1, 1, EPI_F32><<<dim3(6, 16, nbg), 256, 0, stream>>>(
        (const f16*)scores, nullptr, vT + (long)b0 * VTS, nullptr,
        (void*)(out + (long)b0 * 1572864), nullptr,
        2048, 4096, 2048, 768, 8388608L, VTS, 1572864L);
  }
}

// Round 4
// 503.469 us; speedup vs baseline: 1.1999x; 1.0500x over previous
//
#include <hip/hip_runtime.h>
#include <stdint.h>
#include <type_traits>

typedef __bf16 bf16;
typedef _Float16 f16;
typedef bf16 bf16x8 __attribute__((ext_vector_type(8)));
typedef f16 f16x8 __attribute__((ext_vector_type(8)));
typedef float f32x4 __attribute__((ext_vector_type(4)));

#define LOG2E 1.4426950408889634f
#define SQRT_E 27.712812921102035f

constexpr int BM = 128, BN = 128, BK = 32;
enum { EPI_F32 = 0, EPI_QK = 1, EPI_VT = 2 };

__device__ __forceinline__ void async16(const void* g, void* l) {
  __builtin_amdgcn_global_load_lds(
      (__attribute__((address_space(1))) void*)(uintptr_t)g,
      (__attribute__((address_space(3))) void*)l, 16, 0, 0);
}

__device__ __forceinline__ f32x4 mfma8(bf16x8 a, bf16x8 b, f32x4 c) {
  return __builtin_amdgcn_mfma_f32_16x16x32_bf16(a, b, c, 0, 0, 0);
}
__device__ __forceinline__ f32x4 mfma8(f16x8 a, f16x8 b, f32x4 c) {
  return __builtin_amdgcn_mfma_f32_16x16x32_f16(a, b, c, 0, 0, 0);
}

// C[M,N] = A[M,K] * B[N,K]^T (NT layout, K contiguous in both operands).
// AT/BT = digit tensors per operand. Terms: hh (+ ah*bl if BT==2) (+ al*bh if AT==2).
// Bl has its own leading dim / batch stride (ldbl, stBl).
template <typename T, typename TO, int AT, int BT, int EPI>
__global__ __launch_bounds__(256)
void gemm_kernel(const T* __restrict__ Ah, const T* __restrict__ Al,
                 const T* __restrict__ Bh, const T* __restrict__ Bl,
                 void* __restrict__ C0, void* __restrict__ C1,
                 int K, long lda, long ldb, long ldbl, long ldc,
                 long stA, long stB, long stBl, long stC) {
  using vec8 = typename std::conditional<std::is_same<T, bf16>::value,
                                         bf16x8, f16x8>::type;
  __shared__ __align__(16) T sAh[BM * BK];
  __shared__ __align__(16) T sBh[BN * BK];
  __shared__ __align__(16) T sAl[AT == 2 ? BM * BK : 8];
  __shared__ __align__(16) T sBl[BT == 2 ? BN * BK : 8];

  const int z = blockIdx.z;
  const T* pAh = Ah + (long)z * stA;
  const T* pBh = Bh + (long)z * stB;
  const T* pAl = (AT == 2) ? (Al + (long)z * stA) : nullptr;
  const T* pBl = (BT == 2) ? (Bl + (long)z * stBl) : nullptr;

  const int bm = blockIdx.y * BM;
  const int bn = blockIdx.x * BN;
  const int tid = threadIdx.x;
  const int wave = tid >> 6;
  const int lane = tid & 63;
  const int wm = (wave & 1) * 64;
  const int wn = (wave >> 1) * 64;
  const int quad = lane >> 4;
  const int l16 = lane & 15;

  f32x4 acc[4][4] = {};

  const int r0 = tid >> 2;        // staging row 0..63
  const int p0 = (tid & 3) * 8;   // staging k-offset (elements)

  for (int kt = 0; kt < K; kt += BK) {
    __syncthreads();
    {
      const long ka = kt + p0;
      async16(pAh + (long)(bm + r0) * lda + ka,      &sAh[tid * 8]);
      async16(pAh + (long)(bm + 64 + r0) * lda + ka, &sAh[(tid + 256) * 8]);
      async16(pBh + (long)(bn + r0) * ldb + ka,      &sBh[tid * 8]);
      async16(pBh + (long)(bn + 64 + r0) * ldb + ka, &sBh[(tid + 256) * 8]);
      if constexpr (AT == 2) {
        async16(pAl + (long)(bm + r0) * lda + ka,      &sAl[tid * 8]);
        async16(pAl + (long)(bm + 64 + r0) * lda + ka, &sAl[(tid + 256) * 8]);
      }
      if constexpr (BT == 2) {
        async16(pBl + (long)(bn + r0) * ldbl + ka,      &sBl[tid * 8]);
        async16(pBl + (long)(bn + 64 + r0) * ldbl + ka, &sBl[(tid + 256) * 8]);
      }
    }
    __syncthreads();

    vec8 ah[4], al[4];
#pragma unroll
    for (int i = 0; i < 4; ++i) {
      ah[i] = *(const vec8*)&sAh[(wm + i * 16 + l16) * BK + quad * 8];
      if constexpr (AT == 2)
        al[i] = *(const vec8*)&sAl[(wm + i * 16 + l16) * BK + quad * 8];
    }
#pragma unroll
    for (int j = 0; j < 4; ++j) {
      const vec8 bh = *(const vec8*)&sBh[(wn + j * 16 + l16) * BK + quad * 8];
      vec8 bl;
      if constexpr (BT == 2)
        bl = *(const vec8*)&sBl[(wn + j * 16 + l16) * BK + quad * 8];
#pragma unroll
      for (int i = 0; i < 4; ++i) {
        acc[i][j] = mfma8(ah[i], bh, acc[i][j]);
        if constexpr (BT == 2) acc[i][j] = mfma8(ah[i], bl, acc[i][j]);
        if constexpr (AT == 2) acc[i][j] = mfma8(al[i], bh, acc[i][j]);
      }
    }
  }

  // C/D frag mapping (m89/m91 verified): col = lane&15, row = quad*4 + reg
  if constexpr (EPI == EPI_F32) {
    float* C = (float*)C0 + (long)z * stC;
#pragma unroll
    for (int i = 0; i < 4; ++i) {
      const int mb = bm + wm + i * 16 + quad * 4;
#pragma unroll
      for (int j = 0; j < 4; ++j) {
        const int n = bn + wn + j * 16 + l16;
#pragma unroll
        for (int r = 0; r < 4; ++r)
          C[(long)(mb + r) * ldc + n] = acc[i][j][r];
      }
    }
  } else if constexpr (EPI == EPI_QK) {
    // C0 = qk_h [M, ldc]; C1 = k_l [M, ldc/2]; lo written only for n >= ldc/2
    TO* Ch = (TO*)C0;
    TO* Cl = (TO*)C1;
    const long half = ldc >> 1;
    const bool is_k = (bn >= half);  // block-uniform (BN divides half)
#pragma unroll
    for (int i = 0; i < 4; ++i) {
      const int mb = bm + wm + i * 16 + quad * 4;
#pragma unroll
      for (int j = 0; j < 4; ++j) {
        const int n = bn + wn + j * 16 + l16;
#pragma unroll
        for (int r = 0; r < 4; ++r) {
          const float f = acc[i][j][r];
          const TO h = (TO)f;
          Ch[(long)(mb + r) * ldc + n] = h;
          if (is_k)
            Cl[(long)(mb + r) * half + (n - half)] = (TO)(f - (float)h);
        }
      }
    }
  } else {  // EPI_VT: C0 = vT [8][768][2048], global row m -> (m>>11, m&2047)
    TO* vT = (TO*)C0;
#pragma unroll
    for (int i = 0; i < 4; ++i) {
      const int mb = bm + wm + i * 16 + quad * 4;
      const long bb = mb >> 11;
      const long ml = mb & 2047;
#pragma unroll
      for (int j = 0; j < 4; ++j) {
        const int e = bn + wn + j * 16 + l16;
        union { TO b[4]; uint2 u; } P;
#pragma unroll
        for (int r = 0; r < 4; ++r) P.b[r] = (TO)acc[i][j][r];
        *(uint2*)&vT[(bb * 768 + e) * 2048 + ml] = P.u;
      }
    }
  }
}

// One block per score row (2048 fp32). Writes normalized p * (1/sqrt(768)) as
// f16 IN-PLACE into the first quarter of the row's fp32 storage (all global
// reads are register-held before the final barriers; writes after).
__global__ __launch_bounds__(256)
void softmax_kernel(float* __restrict__ sc) {
  __shared__ float red[4];
  float* srow = sc + (long)blockIdx.x * 2048;
  const int tid = threadIdx.x;
  const int wave = tid >> 6;
  const int lane = tid & 63;
  const float4 v0 = *(const float4*)(srow + tid * 4);
  const float4 v1 = *(const float4*)(srow + 1024 + tid * 4);
  float mx = fmaxf(fmaxf(fmaxf(v0.x, v0.y), fmaxf(v0.z, v0.w)),
                   fmaxf(fmaxf(v1.x, v1.y), fmaxf(v1.z, v1.w)));
#pragma unroll
  for (int o = 32; o >= 1; o >>= 1) mx = fmaxf(mx, __shfl_xor(mx, o));
  if (lane == 0) red[wave] = mx;
  __syncthreads();
  mx = fmaxf(fmaxf(red[0], red[1]), fmaxf(red[2], red[3]));
  const float e0 = exp2f((v0.x - mx) * LOG2E);
  const float e1 = exp2f((v0.y - mx) * LOG2E);
  const float e2 = exp2f((v0.z - mx) * LOG2E);
  const float e3 = exp2f((v0.w - mx) * LOG2E);
  const float e4 = exp2f((v1.x - mx) * LOG2E);
  const float e5 = exp2f((v1.y - mx) * LOG2E);
  const float e6 = exp2f((v1.z - mx) * LOG2E);
  const float e7 = exp2f((v1.w - mx) * LOG2E);
  float s = ((e0 + e1) + (e2 + e3)) + ((e4 + e5) + (e6 + e7));
#pragma unroll
  for (int o = 32; o >= 1; o >>= 1) s += __shfl_xor(s, o);
  __syncthreads();  // everyone done reading red[] for max
  if (lane == 0) red[wave] = s;
  __syncthreads();
  s = red[0] + red[1] + red[2] + red[3];
  const float inv = 1.0f / (s * SQRT_E);
  f16* prow = (f16*)srow;
  union { f16 b[4]; uint2 u; } P;
  P.b[0] = (f16)(e0 * inv); P.b[1] = (f16)(e1 * inv);
  P.b[2] = (f16)(e2 * inv); P.b[3] = (f16)(e3 * inv);
  *(uint2*)(prow + tid * 4) = P.u;
  P.b[0] = (f16)(e4 * inv); P.b[1] = (f16)(e5 * inv);
  P.b[2] = (f16)(e6 * inv); P.b[3] = (f16)(e7 * inv);
  *(uint2*)(prow + 1024 + tid * 4) = P.u;
}

// Fused fp32 -> f16 conversion: x -> hi/lo pair; Wq|Wk -> single (concat); Wv -> single.
__global__ __launch_bounds__(256)
void split_all(const float4* __restrict__ x, const float4* __restrict__ wq,
               const float4* __restrict__ wk, const float4* __restrict__ wv,
               uint2* __restrict__ xh, uint2* __restrict__ xl,
               uint2* __restrict__ wqkh, uint2* __restrict__ wvh) {
  constexpr int NX = 3145728;   // x float4 count
  constexpr int NW = 147456;    // per-W float4 count
  const int i = blockIdx.x * 256 + threadIdx.x;
  float4 v;
  uint2 *dh, *dl;
  if (i < NX) {
    v = x[i]; dh = xh + i; dl = xl + i;
  } else {
    const int j = i - NX;
    if (j < 2 * NW) {
      v = (j < NW) ? wq[j] : wk[j - NW];
      dh = wqkh + j; dl = nullptr;
    } else {
      const int m = j - 2 * NW;
      v = wv[m]; dh = wvh + m; dl = nullptr;
    }
  }
  const f16 h0 = (f16)v.x, h1 = (f16)v.y, h2 = (f16)v.z, h3 = (f16)v.w;
  union { f16 b[4]; uint2 u; } P;
  P.b[0] = h0; P.b[1] = h1; P.b[2] = h2; P.b[3] = h3;
  *dh = P.u;
  if (dl != nullptr) {
    P.b[0] = (f16)(v.x - (float)h0);
    P.b[1] = (f16)(v.y - (float)h1);
    P.b[2] = (f16)(v.z - (float)h2);
    P.b[3] = (f16)(v.w - (float)h3);
    *dl = P.u;
  }
}

extern "C" void kernel_launch(void* const* d_in, const int* in_sizes, int n_in,
                              void* d_out, int out_size, void* d_ws, size_t ws_size,
                              hipStream_t stream) {
  const float* x  = (const float*)d_in[0];
  const float* Wq = (const float*)d_in[1];
  const float* Wk = (const float*)d_in[2];
  const float* Wv = (const float*)d_in[3];
  float* out = (float*)d_out;
  char* ws = (char*)d_ws;

  // ---- workspace layout (bytes) ----
  // persistent: qk_h f16 [16384,1536] + k_l f16 [16384,768] + vT f16 [8][768][2048]
  const size_t SZQKH = 50331648;   // 16384*1536*2
  const size_t SZKL  = 25165824;   // 16384*768*2
  const size_t SZVT  = 25165824;
  f16* qkh = (f16*)(ws + 0);
  f16* kl  = (f16*)(ws + SZQKH);
  f16* vT  = (f16*)(ws + SZQKH + SZKL);
  const size_t PERS = SZQKH + SZKL + SZVT;  // 100663296
  // phase-1 temps (dead after projections); scores slabs overlay them
  const size_t SZX = 25165824;     // 16384*768 f16
  f16* xh   = (f16*)(ws + PERS);
  f16* xl   = (f16*)(ws + PERS + SZX);
  f16* wqkh = (f16*)(ws + PERS + 2 * SZX);            // 1536*768 f16 = 2359296
  f16* wvh  = (f16*)(ws + PERS + 2 * SZX + 2359296);  // 768*768 f16 = 1179648
  float* scores = (float*)(ws + PERS);

  long avail = (long)ws_size - (long)PERS;
  int nb = (int)(avail / 16777216);  // fp32 [2048,2048] score slabs that fit
  if (nb < 1) nb = 1;
  if (nb > 8) nb = 8;

  // ---- phase 1: fused convert/split + projections ----
  split_all<<<14016, 256, 0, stream>>>(
      (const float4*)x, (const float4*)Wq, (const float4*)Wk, (const float4*)Wv,
      (uint2*)xh, (uint2*)xl, (uint2*)wqkh, (uint2*)wvh);

  // q|k projection: (xh+xl) [16384,768] x wqk_h [1536,768]^T, 2-term, f16.
  // Epilogue: q cols (n<768) hi only; k cols hi+lo.
  gemm_kernel<f16, f16, 2, 1, EPI_QK><<<dim3(12, 128, 1), 256, 0, stream>>>(
      xh, xl, wqkh, nullptr, (void*)qkh, (void*)kl,
      768, 768, 768, 0, 1536, 0, 0, 0, 0);
  // v projection -> vT f16 transposed (1-term)
  gemm_kernel<f16, f16, 1, 1, EPI_VT><<<dim3(6, 128, 1), 256, 0, stream>>>(
      xh, nullptr, wvh, nullptr, (void*)vT, nullptr,
      768, 768, 768, 0, 0, 0, 0, 0, 0);

  // ---- phase 2: scores -> softmax -> PV ----
  const long QKS = 3145728;  // 2048*1536 (qk_h batch stride, elements)
  const long KLS = 1572864;  // 2048*768  (k_l batch stride)
  const long VTS = 1572864;  // 768*2048
  for (int b0 = 0; b0 < 8; b0 += nb) {
    const int nbg = (8 - b0 < nb) ? (8 - b0) : nb;
    // S = qh*kh^T + qh*kl^T  (A = qh single, B = kh + kl)
    gemm_kernel<f16, float, 1, 2, EPI_F32><<<dim3(16, 16, nbg), 256, 0, stream>>>(
        qkh + (long)b0 * QKS, nullptr,
        qkh + 768 + (long)b0 * QKS, kl + (long)b0 * KLS,
        (void*)scores, nullptr,
        768, 1536, 1536, 768, 2048, QKS, QKS, KLS, 4194304L);
    softmax_kernel<<<nbg * 2048, 256, 0, stream>>>(scores);
    // O = P * vT^T  (P f16 rows embedded in fp32 score rows, pitch 4096 elems)
    gemm_kernel<f16, float, 1, 1, EPI_F32><<<dim3(6, 16, nbg), 256, 0, stream>>>(
        (const f16*)scores, nullptr, vT + (long)b0 * VTS, nullptr,
        (void*)(out + (long)b0 * 1572864), nullptr,
        2048, 4096, 2048, 0, 768, 8388608L, VTS, 0, 1572864L);
  }
}

// Round 5
// 466.608 us; speedup vs baseline: 1.2947x; 1.0790x over previous
//
#include <hip/hip_runtime.h>
#include <stdint.h>
#include <type_traits>

typedef __bf16 bf16;
typedef _Float16 f16;
typedef bf16 bf16x8 __attribute__((ext_vector_type(8)));
typedef f16 f16x8 __attribute__((ext_vector_type(8)));
typedef float f32x4 __attribute__((ext_vector_type(4)));

#define LOG2E 1.4426950408889634f
#define SQRT_E 27.712812921102035f

constexpr int BM = 128, BN = 128, BK = 32;
enum { EPI_F32 = 0, EPI_PAIR = 1, EPI_VT = 2 };

__device__ __forceinline__ void async16(const void* g, void* l) {
  __builtin_amdgcn_global_load_lds(
      (__attribute__((address_space(1))) void*)(uintptr_t)g,
      (__attribute__((address_space(3))) void*)l, 16, 0, 0);
}

__device__ __forceinline__ f32x4 mfma8(bf16x8 a, bf16x8 b, f32x4 c) {
  return __builtin_amdgcn_mfma_f32_16x16x32_bf16(a, b, c, 0, 0, 0);
}
__device__ __forceinline__ f32x4 mfma8(f16x8 a, f16x8 b, f32x4 c) {
  return __builtin_amdgcn_mfma_f32_16x16x32_f16(a, b, c, 0, 0, 0);
}

// C[M,N] = A[M,K] * B[N,K]^T (NT layout, K contiguous in both operands).
// AT/BT = digit tensors per operand. Terms: ah*bh (+ ah*bl if BT==2) (+ al*bh if AT==2).
template <typename T, typename TO, int AT, int BT, int EPI>
__global__ __launch_bounds__(256)
void gemm_kernel(const T* __restrict__ Ah, const T* __restrict__ Al,
                 const T* __restrict__ Bh, const T* __restrict__ Bl,
                 void* __restrict__ C0, void* __restrict__ C1,
                 int K, long lda, long ldb, long ldbl, long ldc,
                 long stA, long stB, long stBl, long stC) {
  using vec8 = typename std::conditional<std::is_same<T, bf16>::value,
                                         bf16x8, f16x8>::type;
  __shared__ __align__(16) T sAh[BM * BK];
  __shared__ __align__(16) T sBh[BN * BK];
  __shared__ __align__(16) T sAl[AT == 2 ? BM * BK : 8];
  __shared__ __align__(16) T sBl[BT == 2 ? BN * BK : 8];

  const int z = blockIdx.z;
  const T* pAh = Ah + (long)z * stA;
  const T* pBh = Bh + (long)z * stB;
  const T* pAl = (AT == 2) ? (Al + (long)z * stA) : nullptr;
  const T* pBl = (BT == 2) ? (Bl + (long)z * stBl) : nullptr;

  const int bm = blockIdx.y * BM;
  const int bn = blockIdx.x * BN;
  const int tid = threadIdx.x;
  const int wave = tid >> 6;
  const int lane = tid & 63;
  const int wm = (wave & 1) * 64;
  const int wn = (wave >> 1) * 64;
  const int quad = lane >> 4;
  const int l16 = lane & 15;

  f32x4 acc[4][4] = {};

  const int r0 = tid >> 2;        // staging row 0..63
  const int p0 = (tid & 3) * 8;   // staging k-offset (elements)

  for (int kt = 0; kt < K; kt += BK) {
    __syncthreads();
    {
      const long ka = kt + p0;
      async16(pAh + (long)(bm + r0) * lda + ka,      &sAh[tid * 8]);
      async16(pAh + (long)(bm + 64 + r0) * lda + ka, &sAh[(tid + 256) * 8]);
      async16(pBh + (long)(bn + r0) * ldb + ka,      &sBh[tid * 8]);
      async16(pBh + (long)(bn + 64 + r0) * ldb + ka, &sBh[(tid + 256) * 8]);
      if constexpr (AT == 2) {
        async16(pAl + (long)(bm + r0) * lda + ka,      &sAl[tid * 8]);
        async16(pAl + (long)(bm + 64 + r0) * lda + ka, &sAl[(tid + 256) * 8]);
      }
      if constexpr (BT == 2) {
        async16(pBl + (long)(bn + r0) * ldbl + ka,      &sBl[tid * 8]);
        async16(pBl + (long)(bn + 64 + r0) * ldbl + ka, &sBl[(tid + 256) * 8]);
      }
    }
    __syncthreads();

    vec8 ah[4], al[4];
#pragma unroll
    for (int i = 0; i < 4; ++i) {
      ah[i] = *(const vec8*)&sAh[(wm + i * 16 + l16) * BK + quad * 8];
      if constexpr (AT == 2)
        al[i] = *(const vec8*)&sAl[(wm + i * 16 + l16) * BK + quad * 8];
    }
#pragma unroll
    for (int j = 0; j < 4; ++j) {
      const vec8 bh = *(const vec8*)&sBh[(wn + j * 16 + l16) * BK + quad * 8];
      vec8 bl;
      if constexpr (BT == 2)
        bl = *(const vec8*)&sBl[(wn + j * 16 + l16) * BK + quad * 8];
#pragma unroll
      for (int i = 0; i < 4; ++i) {
        acc[i][j] = mfma8(ah[i], bh, acc[i][j]);
        if constexpr (BT == 2) acc[i][j] = mfma8(ah[i], bl, acc[i][j]);
        if constexpr (AT == 2) acc[i][j] = mfma8(al[i], bh, acc[i][j]);
      }
    }
  }

  // C/D frag mapping (m89/m91 verified): col = lane&15, row = quad*4 + reg
  if constexpr (EPI == EPI_F32) {
    float* C = (float*)C0 + (long)z * stC;
#pragma unroll
    for (int i = 0; i < 4; ++i) {
      const int mb = bm + wm + i * 16 + quad * 4;
#pragma unroll
      for (int j = 0; j < 4; ++j) {
        const int n = bn + wn + j * 16 + l16;
#pragma unroll
        for (int r = 0; r < 4; ++r)
          C[(long)(mb + r) * ldc + n] = acc[i][j][r];
      }
    }
  } else if constexpr (EPI == EPI_PAIR) {
    // C0 = hi [M, ldc], C1 = lo [M, ldc]
    TO* Ch = (TO*)C0;
    TO* Cl = (TO*)C1;
#pragma unroll
    for (int i = 0; i < 4; ++i) {
      const int mb = bm + wm + i * 16 + quad * 4;
#pragma unroll
      for (int j = 0; j < 4; ++j) {
        const int n = bn + wn + j * 16 + l16;
#pragma unroll
        for (int r = 0; r < 4; ++r) {
          const float f = acc[i][j][r];
          const TO h = (TO)f;
          const long idx = (long)(mb + r) * ldc + n;
          Ch[idx] = h;
          Cl[idx] = (TO)(f - (float)h);
        }
      }
    }
  } else {  // EPI_VT: C0 = vT [8][768][2048], global row m -> (m>>11, m&2047)
    TO* vT = (TO*)C0;
#pragma unroll
    for (int i = 0; i < 4; ++i) {
      const int mb = bm + wm + i * 16 + quad * 4;
      const long bb = mb >> 11;
      const long ml = mb & 2047;
#pragma unroll
      for (int j = 0; j < 4; ++j) {
        const int e = bn + wn + j * 16 + l16;
        union { TO b[4]; uint2 u; } P;
#pragma unroll
        for (int r = 0; r < 4; ++r) P.b[r] = (TO)acc[i][j][r];
        *(uint2*)&vT[(bb * 768 + e) * 2048 + ml] = P.u;
      }
    }
  }
}

// One block per score row (2048 fp32). Writes normalized p * (1/sqrt(768)) as
// f16 IN-PLACE into the first quarter of the row's fp32 storage.
__global__ __launch_bounds__(256)
void softmax_kernel(float* __restrict__ sc) {
  __shared__ float red[4];
  float* srow = sc + (long)blockIdx.x * 2048;
  const int tid = threadIdx.x;
  const int wave = tid >> 6;
  const int lane = tid & 63;
  const float4 v0 = *(const float4*)(srow + tid * 4);
  const float4 v1 = *(const float4*)(srow + 1024 + tid * 4);
  float mx = fmaxf(fmaxf(fmaxf(v0.x, v0.y), fmaxf(v0.z, v0.w)),
                   fmaxf(fmaxf(v1.x, v1.y), fmaxf(v1.z, v1.w)));
#pragma unroll
  for (int o = 32; o >= 1; o >>= 1) mx = fmaxf(mx, __shfl_xor(mx, o));
  if (lane == 0) red[wave] = mx;
  __syncthreads();
  mx = fmaxf(fmaxf(red[0], red[1]), fmaxf(red[2], red[3]));
  const float e0 = exp2f((v0.x - mx) * LOG2E);
  const float e1 = exp2f((v0.y - mx) * LOG2E);
  const float e2 = exp2f((v0.z - mx) * LOG2E);
  const float e3 = exp2f((v0.w - mx) * LOG2E);
  const float e4 = exp2f((v1.x - mx) * LOG2E);
  const float e5 = exp2f((v1.y - mx) * LOG2E);
  const float e6 = exp2f((v1.z - mx) * LOG2E);
  const float e7 = exp2f((v1.w - mx) * LOG2E);
  float s = ((e0 + e1) + (e2 + e3)) + ((e4 + e5) + (e6 + e7));
#pragma unroll
  for (int o = 32; o >= 1; o >>= 1) s += __shfl_xor(s, o);
  __syncthreads();  // everyone done reading red[] for max
  if (lane == 0) red[wave] = s;
  __syncthreads();
  s = red[0] + red[1] + red[2] + red[3];
  const float inv = 1.0f / (s * SQRT_E);
  f16* prow = (f16*)srow;
  union { f16 b[4]; uint2 u; } P;
  P.b[0] = (f16)(e0 * inv); P.b[1] = (f16)(e1 * inv);
  P.b[2] = (f16)(e2 * inv); P.b[3] = (f16)(e3 * inv);
  *(uint2*)(prow + tid * 4) = P.u;
  P.b[0] = (f16)(e4 * inv); P.b[1] = (f16)(e5 * inv);
  P.b[2] = (f16)(e6 * inv); P.b[3] = (f16)(e7 * inv);
  *(uint2*)(prow + 1024 + tid * 4) = P.u;
}

// Fused fp32 -> f16: x -> hi/lo pair; Wv -> single.
__global__ __launch_bounds__(256)
void split_all(const float4* __restrict__ x, const float4* __restrict__ wv,
               uint2* __restrict__ xh, uint2* __restrict__ xl,
               uint2* __restrict__ wvh) {
  constexpr int NX = 3145728;   // x float4 count
  constexpr int NWV = 147456;   // Wv float4 count
  const int i = blockIdx.x * 256 + threadIdx.x;
  float4 v;
  uint2 *dh, *dl;
  if (i < NX) {
    v = x[i]; dh = xh + i; dl = xl + i;
  } else {
    const int m = i - NX;
    if (m >= NWV) return;
    v = wv[m]; dh = wvh + m; dl = nullptr;
  }
  const f16 h0 = (f16)v.x, h1 = (f16)v.y, h2 = (f16)v.z, h3 = (f16)v.w;
  union { f16 b[4]; uint2 u; } P;
  P.b[0] = h0; P.b[1] = h1; P.b[2] = h2; P.b[3] = h3;
  *dh = P.u;
  if (dl != nullptr) {
    P.b[0] = (f16)(v.x - (float)h0);
    P.b[1] = (f16)(v.y - (float)h1);
    P.b[2] = (f16)(v.z - (float)h2);
    P.b[3] = (f16)(v.w - (float)h3);
    *dl = P.u;
  }
}

// Transpose 768x768 fp32 W[e][d] -> f16 hi/lo pair WT[d][e] (e contiguous).
// z=0: Wq, z=1: Wk. 64x64 tiles, 256 threads.
__global__ __launch_bounds__(256)
void transpose_split(const float* __restrict__ Wq, const float* __restrict__ Wk,
                     f16* __restrict__ qTh, f16* __restrict__ qTl,
                     f16* __restrict__ kTh, f16* __restrict__ kTl) {
  __shared__ float tile[64][65];
  const float* src = blockIdx.z ? Wk : Wq;
  f16* dh = blockIdx.z ? kTh : qTh;
  f16* dl = blockIdx.z ? kTl : qTl;
  const int e0 = blockIdx.y * 64, d0 = blockIdx.x * 64;
  const int t = threadIdx.x;
  const int r = t >> 2;            // 0..63
  const int c4 = (t & 3) * 16;     // 0,16,32,48
  const float4* s4 = (const float4*)(src + (long)(e0 + r) * 768 + d0 + c4);
#pragma unroll
  for (int g = 0; g < 4; ++g) {
    const float4 v = s4[g];
    tile[r][c4 + g * 4 + 0] = v.x;
    tile[r][c4 + g * 4 + 1] = v.y;
    tile[r][c4 + g * 4 + 2] = v.z;
    tile[r][c4 + g * 4 + 3] = v.w;
  }
  __syncthreads();
  // write row d = d0+r, cols e0+c4 .. +15 (32B contiguous per thread)
  union { f16 b[8]; uint4 u; } H0, H1, L0, L1;
#pragma unroll
  for (int i = 0; i < 16; ++i) {
    const float v = tile[c4 + i][r];
    const f16 h = (f16)v;
    const f16 l = (f16)(v - (float)h);
    if (i < 8) { H0.b[i] = h; L0.b[i] = l; }
    else       { H1.b[i - 8] = h; L1.b[i - 8] = l; }
  }
  const long o = (long)(d0 + r) * 768 + e0 + c4;
  *(uint4*)(dh + o) = H0.u;  *(uint4*)(dh + o + 8) = H1.u;
  *(uint4*)(dl + o) = L0.u;  *(uint4*)(dl + o + 8) = L1.u;
}

extern "C" void kernel_launch(void* const* d_in, const int* in_sizes, int n_in,
                              void* d_out, int out_size, void* d_ws, size_t ws_size,
                              hipStream_t stream) {
  const float* x  = (const float*)d_in[0];
  const float* Wq = (const float*)d_in[1];
  const float* Wk = (const float*)d_in[2];
  const float* Wv = (const float*)d_in[3];
  float* out = (float*)d_out;
  char* ws = (char*)d_ws;

  // ---- workspace layout (bytes) ----
  // persistent through phase 2: yh, yl, xh [16384,768] f16 + vT [8][768][2048] f16
  const size_t SZ = 25165824;      // 16384*768*2
  f16* yh = (f16*)(ws + 0 * SZ);
  f16* yl = (f16*)(ws + 1 * SZ);
  f16* xh = (f16*)(ws + 2 * SZ);
  f16* vT = (f16*)(ws + 3 * SZ);
  const size_t PERS = 4 * SZ;      // 100663296
  // phase-1 temps (dead after projections); scores slabs overlay them
  const size_t WT = 1179648;       // 768*768 f16
  f16* xl   = (f16*)(ws + PERS);
  f16* wqTh = (f16*)(ws + PERS + SZ);
  f16* wqTl = (f16*)(ws + PERS + SZ + 1 * WT);
  f16* wkTh = (f16*)(ws + PERS + SZ + 2 * WT);
  f16* wkTl = (f16*)(ws + PERS + SZ + 3 * WT);
  f16* mtH  = (f16*)(ws + PERS + SZ + 4 * WT);
  f16* mtL  = (f16*)(ws + PERS + SZ + 5 * WT);
  f16* wvh  = (f16*)(ws + PERS + SZ + 6 * WT);
  float* scores = (float*)(ws + PERS);

  long avail = (long)ws_size - (long)PERS;
  int nb = (int)(avail / 16777216);  // fp32 [2048,2048] score slabs that fit
  if (nb < 1) nb = 1;
  if (nb > 8) nb = 8;

  // ---- phase 1 ----
  split_all<<<12864, 256, 0, stream>>>(
      (const float4*)x, (const float4*)Wv, (uint2*)xh, (uint2*)xl, (uint2*)wvh);
  transpose_split<<<dim3(12, 12, 2), 256, 0, stream>>>(
      Wq, Wk, wqTh, wqTl, wkTh, wkTl);

  // M^T[d'][d] = sum_e WkT[d'][e] * WqT[d][e]  (3-term, f16 pair out)
  gemm_kernel<f16, f16, 2, 2, EPI_PAIR><<<dim3(6, 6, 1), 256, 0, stream>>>(
      wkTh, wkTl, wqTh, wqTl, (void*)mtH, (void*)mtL,
      768, 768, 768, 768, 768, 0, 0, 0, 0);

  // y = (xh+xl) * MT_h^T : [16384,768] -> f16 pair (2-term)
  gemm_kernel<f16, f16, 2, 1, EPI_PAIR><<<dim3(6, 128, 1), 256, 0, stream>>>(
      xh, xl, mtH, nullptr, (void*)yh, (void*)yl,
      768, 768, 768, 0, 768, 0, 0, 0, 0);

  // v = xh * Wv_h^T -> vT f16 transposed (1-term)
  gemm_kernel<f16, f16, 1, 1, EPI_VT><<<dim3(6, 128, 1), 256, 0, stream>>>(
      xh, nullptr, wvh, nullptr, (void*)vT, nullptr,
      768, 768, 768, 0, 0, 0, 0, 0, 0);

  // ---- phase 2: scores -> softmax -> PV ----
  const long RS = 1572864;   // 2048*768 (y/x batch stride, elements)
  const long VTS = 1572864;  // 768*2048
  for (int b0 = 0; b0 < 8; b0 += nb) {
    const int nbg = (8 - b0 < nb) ? (8 - b0) : nb;
    // S = yh * xh^T  (1-term)
    gemm_kernel<f16, float, 1, 1, EPI_F32><<<dim3(16, 16, nbg), 256, 0, stream>>>(
        yh + (long)b0 * RS, nullptr, xh + (long)b0 * RS, nullptr,
        (void*)scores, nullptr,
        768, 768, 768, 0, 2048, RS, RS, 0, 4194304L);
    softmax_kernel<<<nbg * 2048, 256, 0, stream>>>(scores);
    // O = P * vT^T  (P f16 rows embedded in fp32 score rows, pitch 4096 elems)
    gemm_kernel<f16, float, 1, 1, EPI_F32><<<dim3(6, 16, nbg), 256, 0, stream>>>(
        (const f16*)scores, nullptr, vT + (long)b0 * VTS, nullptr,
        (void*)(out + (long)b0 * 1572864), nullptr,
        2048, 4096, 2048, 0, 768, 8388608L, VTS, 0, 1572864L);
  }
}

// Round 6
// 408.062 us; speedup vs baseline: 1.4805x; 1.1435x over previous
//
#include <hip/hip_runtime.h>
#include <stdint.h>
#include <type_traits>

typedef __bf16 bf16;
typedef _Float16 f16;
typedef bf16 bf16x8 __attribute__((ext_vector_type(8)));
typedef f16 f16x8 __attribute__((ext_vector_type(8)));
typedef float f32x4 __attribute__((ext_vector_type(4)));

#define LOG2E 1.4426950408889634f
#define SQRT_E 27.712812921102035f

constexpr int BM = 128, BN = 128, BK = 32;
enum { EPI_F32 = 0, EPI_PAIR = 1, EPI_VT = 2 };

__device__ __forceinline__ void async16(const void* g, void* l) {
  __builtin_amdgcn_global_load_lds(
      (__attribute__((address_space(1))) void*)(uintptr_t)g,
      (__attribute__((address_space(3))) void*)l, 16, 0, 0);
}

__device__ __forceinline__ f32x4 mfma8(bf16x8 a, bf16x8 b, f32x4 c) {
  return __builtin_amdgcn_mfma_f32_16x16x32_bf16(a, b, c, 0, 0, 0);
}
__device__ __forceinline__ f32x4 mfma8(f16x8 a, f16x8 b, f32x4 c) {
  return __builtin_amdgcn_mfma_f32_16x16x32_f16(a, b, c, 0, 0, 0);
}

// C[M,N] = A[M,K] * B[N,K]^T (NT layout, K contiguous in both operands).
// AT/BT = digit tensors per operand. Terms: ah*bh (+ ah*bl if BT==2) (+ al*bh if AT==2).
// SWZ==1: launched as 1D grid of gxN*gyM*gz blocks; decode targets id%8 XCD
// round-robin so all gxN N-siblings of an M-strip share one XCD's L2 (A-tile
// reuse) and consecutive strips share the B batch-slab.
template <typename T, typename TO, int AT, int BT, int EPI, int SWZ>
__global__ __launch_bounds__(256)
void gemm_kernel(const T* __restrict__ Ah, const T* __restrict__ Al,
                 const T* __restrict__ Bh, const T* __restrict__ Bl,
                 void* __restrict__ C0, void* __restrict__ C1,
                 int K, long lda, long ldb, long ldbl, long ldc,
                 long stA, long stB, long stBl, long stC,
                 int gxN, int gyM) {
  using vec8 = typename std::conditional<std::is_same<T, bf16>::value,
                                         bf16x8, f16x8>::type;
  __shared__ __align__(16) T sAh[BM * BK];
  __shared__ __align__(16) T sBh[BN * BK];
  __shared__ __align__(16) T sAl[AT == 2 ? BM * BK : 8];
  __shared__ __align__(16) T sBl[BT == 2 ? BN * BK : 8];

  int bxi, byi, z;
  if constexpr (SWZ) {
    const int id = blockIdx.x;
    const int xcd = id & 7;
    const int j = id >> 3;
    const int s = j / gxN;          // strip index on this XCD
    const int n = j - s * gxN;      // N-sibling
    const int g = xcd + 8 * s;      // global strip id
    bxi = n;
    byi = g % gyM;
    z = g / gyM;
  } else {
    bxi = blockIdx.x; byi = blockIdx.y; z = blockIdx.z;
  }

  const T* pAh = Ah + (long)z * stA;
  const T* pBh = Bh + (long)z * stB;
  const T* pAl = (AT == 2) ? (Al + (long)z * stA) : nullptr;
  const T* pBl = (BT == 2) ? (Bl + (long)z * stBl) : nullptr;

  const int bm = byi * BM;
  const int bn = bxi * BN;
  const int tid = threadIdx.x;
  const int wave = tid >> 6;
  const int lane = tid & 63;
  const int wm = (wave & 1) * 64;
  const int wn = (wave >> 1) * 64;
  const int quad = lane >> 4;
  const int l16 = lane & 15;

  f32x4 acc[4][4] = {};

  const int r0 = tid >> 2;        // staging row 0..63
  const int p0 = (tid & 3) * 8;   // staging k-offset (elements)

  for (int kt = 0; kt < K; kt += BK) {
    __syncthreads();
    {
      const long ka = kt + p0;
      async16(pAh + (long)(bm + r0) * lda + ka,      &sAh[tid * 8]);
      async16(pAh + (long)(bm + 64 + r0) * lda + ka, &sAh[(tid + 256) * 8]);
      async16(pBh + (long)(bn + r0) * ldb + ka,      &sBh[tid * 8]);
      async16(pBh + (long)(bn + 64 + r0) * ldb + ka, &sBh[(tid + 256) * 8]);
      if constexpr (AT == 2) {
        async16(pAl + (long)(bm + r0) * lda + ka,      &sAl[tid * 8]);
        async16(pAl + (long)(bm + 64 + r0) * lda + ka, &sAl[(tid + 256) * 8]);
      }
      if constexpr (BT == 2) {
        async16(pBl + (long)(bn + r0) * ldbl + ka,      &sBl[tid * 8]);
        async16(pBl + (long)(bn + 64 + r0) * ldbl + ka, &sBl[(tid + 256) * 8]);
      }
    }
    __syncthreads();

    vec8 ah[4], al[4];
#pragma unroll
    for (int i = 0; i < 4; ++i) {
      ah[i] = *(const vec8*)&sAh[(wm + i * 16 + l16) * BK + quad * 8];
      if constexpr (AT == 2)
        al[i] = *(const vec8*)&sAl[(wm + i * 16 + l16) * BK + quad * 8];
    }
#pragma unroll
    for (int j = 0; j < 4; ++j) {
      const vec8 bh = *(const vec8*)&sBh[(wn + j * 16 + l16) * BK + quad * 8];
      vec8 bl;
      if constexpr (BT == 2)
        bl = *(const vec8*)&sBl[(wn + j * 16 + l16) * BK + quad * 8];
#pragma unroll
      for (int i = 0; i < 4; ++i) {
        acc[i][j] = mfma8(ah[i], bh, acc[i][j]);
        if constexpr (BT == 2) acc[i][j] = mfma8(ah[i], bl, acc[i][j]);
        if constexpr (AT == 2) acc[i][j] = mfma8(al[i], bh, acc[i][j]);
      }
    }
  }

  // C/D frag mapping (m89/m91 verified): col = lane&15, row = quad*4 + reg
  if constexpr (EPI == EPI_F32) {
    float* C = (float*)C0 + (long)z * stC;
#pragma unroll
    for (int i = 0; i < 4; ++i) {
      const int mb = bm + wm + i * 16 + quad * 4;
#pragma unroll
      for (int j = 0; j < 4; ++j) {
        const int n = bn + wn + j * 16 + l16;
#pragma unroll
        for (int r = 0; r < 4; ++r)
          C[(long)(mb + r) * ldc + n] = acc[i][j][r];
      }
    }
  } else if constexpr (EPI == EPI_PAIR) {
    // C0 = hi [M, ldc], C1 = lo [M, ldc]
    TO* Ch = (TO*)C0;
    TO* Cl = (TO*)C1;
#pragma unroll
    for (int i = 0; i < 4; ++i) {
      const int mb = bm + wm + i * 16 + quad * 4;
#pragma unroll
      for (int j = 0; j < 4; ++j) {
        const int n = bn + wn + j * 16 + l16;
#pragma unroll
        for (int r = 0; r < 4; ++r) {
          const float f = acc[i][j][r];
          const TO h = (TO)f;
          const long idx = (long)(mb + r) * ldc + n;
          Ch[idx] = h;
          Cl[idx] = (TO)(f - (float)h);
        }
      }
    }
  } else {  // EPI_VT: C0 = vT [8][768][2048], global row m -> (m>>11, m&2047)
    TO* vT = (TO*)C0;
#pragma unroll
    for (int i = 0; i < 4; ++i) {
      const int mb = bm + wm + i * 16 + quad * 4;
      const long bb = mb >> 11;
      const long ml = mb & 2047;
#pragma unroll
      for (int j = 0; j < 4; ++j) {
        const int e = bn + wn + j * 16 + l16;
        union { TO b[4]; uint2 u; } P;
#pragma unroll
        for (int r = 0; r < 4; ++r) P.b[r] = (TO)acc[i][j][r];
        *(uint2*)&vT[(bb * 768 + e) * 2048 + ml] = P.u;
      }
    }
  }
}

// One block per score row (2048 fp32). Writes normalized p * (1/sqrt(768)) as
// f16 IN-PLACE into the first quarter of the row's fp32 storage.
__global__ __launch_bounds__(256)
void softmax_kernel(float* __restrict__ sc) {
  __shared__ float red[4];
  float* srow = sc + (long)blockIdx.x * 2048;
  const int tid = threadIdx.x;
  const int wave = tid >> 6;
  const int lane = tid & 63;
  const float4 v0 = *(const float4*)(srow + tid * 4);
  const float4 v1 = *(const float4*)(srow + 1024 + tid * 4);
  float mx = fmaxf(fmaxf(fmaxf(v0.x, v0.y), fmaxf(v0.z, v0.w)),
                   fmaxf(fmaxf(v1.x, v1.y), fmaxf(v1.z, v1.w)));
#pragma unroll
  for (int o = 32; o >= 1; o >>= 1) mx = fmaxf(mx, __shfl_xor(mx, o));
  if (lane == 0) red[wave] = mx;
  __syncthreads();
  mx = fmaxf(fmaxf(red[0], red[1]), fmaxf(red[2], red[3]));
  const float e0 = exp2f((v0.x - mx) * LOG2E);
  const float e1 = exp2f((v0.y - mx) * LOG2E);
  const float e2 = exp2f((v0.z - mx) * LOG2E);
  const float e3 = exp2f((v0.w - mx) * LOG2E);
  const float e4 = exp2f((v1.x - mx) * LOG2E);
  const float e5 = exp2f((v1.y - mx) * LOG2E);
  const float e6 = exp2f((v1.z - mx) * LOG2E);
  const float e7 = exp2f((v1.w - mx) * LOG2E);
  float s = ((e0 + e1) + (e2 + e3)) + ((e4 + e5) + (e6 + e7));
#pragma unroll
  for (int o = 32; o >= 1; o >>= 1) s += __shfl_xor(s, o);
  __syncthreads();  // everyone done reading red[] for max
  if (lane == 0) red[wave] = s;
  __syncthreads();
  s = red[0] + red[1] + red[2] + red[3];
  const float inv = 1.0f / (s * SQRT_E);
  f16* prow = (f16*)srow;
  union { f16 b[4]; uint2 u; } P;
  P.b[0] = (f16)(e0 * inv); P.b[1] = (f16)(e1 * inv);
  P.b[2] = (f16)(e2 * inv); P.b[3] = (f16)(e3 * inv);
  *(uint2*)(prow + tid * 4) = P.u;
  P.b[0] = (f16)(e4 * inv); P.b[1] = (f16)(e5 * inv);
  P.b[2] = (f16)(e6 * inv); P.b[3] = (f16)(e7 * inv);
  *(uint2*)(prow + 1024 + tid * 4) = P.u;
}

// Fused fp32 -> f16: x -> hi/lo pair; Wv -> single.
__global__ __launch_bounds__(256)
void split_all(const float4* __restrict__ x, const float4* __restrict__ wv,
               uint2* __restrict__ xh, uint2* __restrict__ xl,
               uint2* __restrict__ wvh) {
  constexpr int NX = 3145728;   // x float4 count
  constexpr int NWV = 147456;   // Wv float4 count
  const int i = blockIdx.x * 256 + threadIdx.x;
  float4 v;
  uint2 *dh, *dl;
  if (i < NX) {
    v = x[i]; dh = xh + i; dl = xl + i;
  } else {
    const int m = i - NX;
    if (m >= NWV) return;
    v = wv[m]; dh = wvh + m; dl = nullptr;
  }
  const f16 h0 = (f16)v.x, h1 = (f16)v.y, h2 = (f16)v.z, h3 = (f16)v.w;
  union { f16 b[4]; uint2 u; } P;
  P.b[0] = h0; P.b[1] = h1; P.b[2] = h2; P.b[3] = h3;
  *dh = P.u;
  if (dl != nullptr) {
    P.b[0] = (f16)(v.x - (float)h0);
    P.b[1] = (f16)(v.y - (float)h1);
    P.b[2] = (f16)(v.z - (float)h2);
    P.b[3] = (f16)(v.w - (float)h3);
    *dl = P.u;
  }
}

// Transpose 768x768 fp32 W[e][d] -> f16 hi/lo pair WT[d][e] (e contiguous).
// z=0: Wq, z=1: Wk. 64x64 tiles, 256 threads.
__global__ __launch_bounds__(256)
void transpose_split(const float* __restrict__ Wq, const float* __restrict__ Wk,
                     f16* __restrict__ qTh, f16* __restrict__ qTl,
                     f16* __restrict__ kTh, f16* __restrict__ kTl) {
  __shared__ float tile[64][65];
  const float* src = blockIdx.z ? Wk : Wq;
  f16* dh = blockIdx.z ? kTh : qTh;
  f16* dl = blockIdx.z ? kTl : qTl;
  const int e0 = blockIdx.y * 64, d0 = blockIdx.x * 64;
  const int t = threadIdx.x;
  const int r = t >> 2;            // 0..63
  const int c4 = (t & 3) * 16;     // 0,16,32,48
  const float4* s4 = (const float4*)(src + (long)(e0 + r) * 768 + d0 + c4);
#pragma unroll
  for (int g = 0; g < 4; ++g) {
    const float4 v = s4[g];
    tile[r][c4 + g * 4 + 0] = v.x;
    tile[r][c4 + g * 4 + 1] = v.y;
    tile[r][c4 + g * 4 + 2] = v.z;
    tile[r][c4 + g * 4 + 3] = v.w;
  }
  __syncthreads();
  // write row d = d0+r, cols e0+c4 .. +15 (32B contiguous per thread)
  union { f16 b[8]; uint4 u; } H0, H1, L0, L1;
#pragma unroll
  for (int i = 0; i < 16; ++i) {
    const float v = tile[c4 + i][r];
    const f16 h = (f16)v;
    const f16 l = (f16)(v - (float)h);
    if (i < 8) { H0.b[i] = h; L0.b[i] = l; }
    else       { H1.b[i - 8] = h; L1.b[i - 8] = l; }
  }
  const long o = (long)(d0 + r) * 768 + e0 + c4;
  *(uint4*)(dh + o) = H0.u;  *(uint4*)(dh + o + 8) = H1.u;
  *(uint4*)(dl + o) = L0.u;  *(uint4*)(dl + o + 8) = L1.u;
}

extern "C" void kernel_launch(void* const* d_in, const int* in_sizes, int n_in,
                              void* d_out, int out_size, void* d_ws, size_t ws_size,
                              hipStream_t stream) {
  const float* x  = (const float*)d_in[0];
  const float* Wq = (const float*)d_in[1];
  const float* Wk = (const float*)d_in[2];
  const float* Wv = (const float*)d_in[3];
  float* out = (float*)d_out;
  char* ws = (char*)d_ws;

  // ---- workspace layout (bytes) ----
  // persistent through phase 2: yh, yl, xh [16384,768] f16 + vT [8][768][2048] f16
  const size_t SZ = 25165824;      // 16384*768*2
  f16* yh = (f16*)(ws + 0 * SZ);
  f16* yl = (f16*)(ws + 1 * SZ);
  f16* xh = (f16*)(ws + 2 * SZ);
  f16* vT = (f16*)(ws + 3 * SZ);
  const size_t PERS = 4 * SZ;      // 100663296
  // phase-1 temps (dead after projections); scores slabs overlay them
  const size_t WT = 1179648;       // 768*768 f16
  f16* xl   = (f16*)(ws + PERS);
  f16* wqTh = (f16*)(ws + PERS + SZ);
  f16* wqTl = (f16*)(ws + PERS + SZ + 1 * WT);
  f16* wkTh = (f16*)(ws + PERS + SZ + 2 * WT);
  f16* wkTl = (f16*)(ws + PERS + SZ + 3 * WT);
  f16* mtH  = (f16*)(ws + PERS + SZ + 4 * WT);
  f16* mtL  = (f16*)(ws + PERS + SZ + 5 * WT);
  f16* wvh  = (f16*)(ws + PERS + SZ + 6 * WT);
  float* scores = (float*)(ws + PERS);

  long avail = (long)ws_size - (long)PERS;
  int nb = (int)(avail / 16777216);  // fp32 [2048,2048] score slabs that fit
  if (nb < 1) nb = 1;
  if (nb > 8) nb = 8;

  // ---- phase 1 ----
  split_all<<<12864, 256, 0, stream>>>(
      (const float4*)x, (const float4*)Wv, (uint2*)xh, (uint2*)xl, (uint2*)wvh);
  transpose_split<<<dim3(12, 12, 2), 256, 0, stream>>>(
      Wq, Wk, wqTh, wqTl, wkTh, wkTl);

  // M^T[d'][d] = sum_e WkT[d'][e] * WqT[d][e]  (3-term, f16 pair out)
  gemm_kernel<f16, f16, 2, 2, EPI_PAIR, 0><<<dim3(6, 6, 1), 256, 0, stream>>>(
      wkTh, wkTl, wqTh, wqTl, (void*)mtH, (void*)mtL,
      768, 768, 768, 768, 768, 0, 0, 0, 0, 0, 0);

  // y = (xh+xl) * MT_h^T : [16384,768] -> f16 pair (2-term), XCD-swizzled
  gemm_kernel<f16, f16, 2, 1, EPI_PAIR, 1><<<768, 256, 0, stream>>>(
      xh, xl, mtH, nullptr, (void*)yh, (void*)yl,
      768, 768, 768, 0, 768, 0, 0, 0, 0, 6, 128);

  // v = xh * Wv_h^T -> vT f16 transposed (1-term), XCD-swizzled
  gemm_kernel<f16, f16, 1, 1, EPI_VT, 1><<<768, 256, 0, stream>>>(
      xh, nullptr, wvh, nullptr, (void*)vT, nullptr,
      768, 768, 768, 0, 0, 0, 0, 0, 0, 6, 128);

  // ---- phase 2: scores -> softmax -> PV ----
  const long RS = 1572864;   // 2048*768 (y/x batch stride, elements)
  const long VTS = 1572864;  // 768*2048
  for (int b0 = 0; b0 < 8; b0 += nb) {
    const int nbg = (8 - b0 < nb) ? (8 - b0) : nb;
    // S = yh * xh^T  (1-term), XCD-swizzled
    gemm_kernel<f16, float, 1, 1, EPI_F32, 1><<<256 * nbg, 256, 0, stream>>>(
        yh + (long)b0 * RS, nullptr, xh + (long)b0 * RS, nullptr,
        (void*)scores, nullptr,
        768, 768, 768, 0, 2048, RS, RS, 0, 4194304L, 16, 16);
    softmax_kernel<<<nbg * 2048, 256, 0, stream>>>(scores);
    // O = P * vT^T  (P f16 rows embedded in fp32 score rows, pitch 4096 elems),
    // XCD-swizzled: 6 N-siblings of each 128-row P-strip share one XCD's L2.
    gemm_kernel<f16, float, 1, 1, EPI_F32, 1><<<96 * nbg, 256, 0, stream>>>(
        (const f16*)scores, nullptr, vT + (long)b0 * VTS, nullptr,
        (void*)(out + (long)b0 * 1572864), nullptr,
        2048, 4096, 2048, 0, 768, 8388608L, VTS, 0, 1572864L, 6, 16);
  }
}